// Round 6
// baseline (152.165 us; speedup 1.0000x reference)
//
#include <hip/hip_runtime.h>
#include <hip/hip_bf16.h>
#include <math.h>

// SkipGRU on MI355X, round 6: persistent 8-step chain kernel with device-scope
// atomic grid barrier; Rt B-fragments preloaded into registers ONCE (192 VGPR)
// and reused across all 8 steps. Graph: 12 -> 6 nodes.
//
// Only chain j=23 contributes to outputs[:, -1, :] (t=191 = chunk 7 lane 23):
// 8 sequential GRU steps over x[:, c*24+23, :], h[256,512].
//
// mfma_f32_16x16x32_bf16 layouts (learn_hip m89-verified):
//   A: lane l holds A[l&15][(l>>4)*8 + j]
//   B: lane l holds B[(l>>4)*8 + j][l&15]  (B^T row-major -> contiguous load)
//   D: lane l reg q -> row (l>>4)*4+q, col l&15

typedef float f32x4 __attribute__((ext_vector_type(4)));
typedef short short8 __attribute__((ext_vector_type(8)));

#define BB 256
#define UU 512
#define KK 512
#define N3 1536
#define NWG 128   // chain kernel workgroups (<= 256 CUs -> co-resident)

__device__ __forceinline__ float sigmoidf_(float s) {
    return 1.0f / (1.0f + __expf(-s));
}

// W[R][C] f32  ->  Wt[C][R] bf16   (LDS-tiled transpose)
__global__ __launch_bounds__(256)
void transpose_bf16(const float* __restrict__ W, __hip_bfloat16* __restrict__ Wt,
                    int R, int C)
{
    __shared__ float tile[32][33];
    const int x = threadIdx.x;          // 0..31
    const int y = threadIdx.y;          // 0..7
    const int c0 = blockIdx.x * 32;
    const int r0 = blockIdx.y * 32;
    #pragma unroll
    for (int i = 0; i < 32; i += 8)
        tile[y + i][x] = W[(long)(r0 + y + i) * C + c0 + x];
    __syncthreads();
    #pragma unroll
    for (int i = 0; i < 32; i += 8)
        Wt[(long)(c0 + y + i) * R + r0 + x] = __float2bfloat16(tile[x][y + i]);
}

// Gather the 8 needed timesteps of x and convert to bf16: Xb[c*256+b][k]
__global__ __launch_bounds__(256)
void convert_x(const float* __restrict__ x, __hip_bfloat16* __restrict__ Xb)
{
    const int idx = blockIdx.x * 256 + threadIdx.x;   // one thread per 8 elems
    const int e = idx * 8;
    const int m = e >> 9;              // 0..2047 = c*256+b
    const int kk = e & 511;
    const int b = m & 255, c = m >> 8;
    const float* src = x + (long)b * (192 * 512) + (long)(c * 24 + 23) * 512 + kk;
    float4 v0 = *(const float4*)src;
    float4 v1 = *(const float4*)(src + 4);
    __hip_bfloat16* dst = Xb + (long)m * 512 + kk;
    dst[0] = __float2bfloat16(v0.x);
    dst[1] = __float2bfloat16(v0.y);
    dst[2] = __float2bfloat16(v0.z);
    dst[3] = __float2bfloat16(v0.w);
    dst[4] = __float2bfloat16(v1.x);
    dst[5] = __float2bfloat16(v1.y);
    dst[6] = __float2bfloat16(v1.z);
    dst[7] = __float2bfloat16(v1.w);
}

// MX = A @ Kt^T + bias:  A[2048][512] bf16, Kt[1536][512] bf16 (=W^T), out f32.
__global__ __launch_bounds__(256)
void gemm_mx(const __hip_bfloat16* __restrict__ A,
             const __hip_bfloat16* __restrict__ Bt,
             const float* __restrict__ bias,
             float* __restrict__ C)
{
    const int tid = threadIdx.x;
    const int lane = tid & 63;
    const int wid = tid >> 6;                    // 0..3
    const int m0 = blockIdx.y * 64 + wid * 16;
    const int n0 = blockIdx.x * 64;
    const int lr = lane & 15;
    const int lk = (lane >> 4) * 8;

    const short8* ap = (const short8*)(A + (long)(m0 + lr) * KK + lk);
    const short8* bp = (const short8*)(Bt + (long)(n0 + lr) * KK + lk);

    f32x4 acc[4] = {{0.f,0.f,0.f,0.f},{0.f,0.f,0.f,0.f},
                    {0.f,0.f,0.f,0.f},{0.f,0.f,0.f,0.f}};
    #pragma unroll
    for (int k = 0; k < 16; ++k) {               // k0 = 32*k
        short8 a = ap[k * 4];
        #pragma unroll
        for (int t = 0; t < 4; ++t) {
            short8 b = bp[t * 1024 + k * 4];     // +16 rows = 16*512/8 short8
            acc[t] = __builtin_amdgcn_mfma_f32_16x16x32_bf16(a, b, acc[t], 0, 0, 0);
        }
    }
    const int row = (lane >> 4) * 4;
    #pragma unroll
    for (int t = 0; t < 4; ++t) {
        const int u = n0 + t * 16 + lr;
        const float bi = bias[u];
        #pragma unroll
        for (int q = 0; q < 4; ++q)
            C[(long)(m0 + row + q) * N3 + u] = acc[t][q] + bi;
    }
}

// Zero the grid-barrier state each replay (ws is poisoned 0xAA once, and gen
// must start at 0 every call for determinism).
__global__ void bar_init(unsigned* bar)
{
    if (threadIdx.x < 2) bar[threadIdx.x] = 0u;
}

__device__ __forceinline__ void grid_sync_(unsigned* bar, unsigned target)
{
    __syncthreads();
    if (threadIdx.x == 0) {
        __threadfence();                                   // release h writes
        if (atomicAdd(&bar[0], 1u) == NWG - 1) {
            atomicExch(&bar[0], 0u);                       // reset count
            __threadfence();
            atomicAdd(&bar[1], 1u);                        // release gen
        } else {
            while (atomicAdd(&bar[1], 0u) < target) { }    // spin
        }
        __threadfence();                                   // acquire
    }
    __syncthreads();
}

// Persistent 8-step GRU chain. 128 WGs x 256 thr; wave owns one 16x16 (m,u)
// tile across all 3 gates and ALL 8 steps; Rt fragments live in registers.
__global__ __launch_bounds__(256, 1)
void gru_chain(const __hip_bfloat16* __restrict__ Rt,   // [1536][512] bf16
               const float* __restrict__ rbias,         // [1536]
               const float* __restrict__ MX,            // [8][256][1536] f32
               float* __restrict__ hfA, __hip_bfloat16* __restrict__ hbA,
               float* __restrict__ hfB, __hip_bfloat16* __restrict__ hbB,
               float* __restrict__ out,                 // [256][512] f32
               unsigned* __restrict__ bar)
{
    const int tid = threadIdx.x;
    const int lane = tid & 63;
    const int wid = tid >> 6;
    const int bx = blockIdx.x & 15;       // n block (16 x 32 cols)
    const int by = blockIdx.x >> 4;       // m block (8 x 32 rows)
    const int wy = wid >> 1, wx = wid & 1;
    const int m0 = by * 32 + wy * 16;
    const int n0 = bx * 32 + wx * 16;
    const int lr = lane & 15;
    const int lk = (lane >> 4) * 8;

    // Preload all B fragments: 3 gates x 16 k-chunks = 48 short8 = 192 VGPR.
    const short8* bp = (const short8*)(Rt + (long)(n0 + lr) * KK + lk);
    short8 B[3][16];
    #pragma unroll
    for (int g = 0; g < 3; ++g)
        #pragma unroll
        for (int k = 0; k < 16; ++k)
            B[g][k] = bp[g * 32768 + k * 4];

    const int row = (lane >> 4) * 4;
    const int u = n0 + lr;
    const float rbz = rbias[u];
    const float rbr = rbias[u + UU];
    const float rbh = rbias[u + 2 * UU];

    #pragma unroll 1
    for (int c = 0; c < 8; ++c) {
        const float* MXc = MX + (long)c * BB * N3;
        const float*          hf_in = (c & 1) ? hfB : hfA;
        const __hip_bfloat16* hb_in = (c & 1) ? hbB : hbA;
        float*          hf_o = (c == 7) ? out : ((c & 1) ? hfA : hfB);
        __hip_bfloat16* hb_o = (c & 1) ? hbA : hbB;

        // Hoist MX / h_old loads (independent of the MFMA chain).
        float mxz[4], mxr[4], mxh[4], hold[4];
        #pragma unroll
        for (int q = 0; q < 4; ++q) {
            const float* mx = MXc + (long)(m0 + row + q) * N3 + u;
            mxz[q] = mx[0];
            mxr[q] = mx[UU];
            mxh[q] = mx[2 * UU];
            hold[q] = (c == 0) ? 0.0f : hf_in[(long)(m0 + row + q) * UU + u];
        }

        f32x4 az = {0.f,0.f,0.f,0.f}, ar = {0.f,0.f,0.f,0.f}, ah = {0.f,0.f,0.f,0.f};
        if (c > 0) {
            const short8* ap = (const short8*)(hb_in + (long)(m0 + lr) * KK + lk);
            short8 A[16];
            #pragma unroll
            for (int k = 0; k < 16; ++k) A[k] = ap[k * 4];
            #pragma unroll
            for (int k = 0; k < 16; ++k) {
                az = __builtin_amdgcn_mfma_f32_16x16x32_bf16(A[k], B[0][k], az, 0, 0, 0);
                ar = __builtin_amdgcn_mfma_f32_16x16x32_bf16(A[k], B[1][k], ar, 0, 0, 0);
                ah = __builtin_amdgcn_mfma_f32_16x16x32_bf16(A[k], B[2][k], ah, 0, 0, 0);
            }
        }

        #pragma unroll
        for (int q = 0; q < 4; ++q) {
            const int m = m0 + row + q;
            const float z = sigmoidf_(mxz[q] + az[q] + rbz);
            const float r = sigmoidf_(mxr[q] + ar[q] + rbr);
            const float cand = mxh[q] + r * (ah[q] + rbh);   // reset_after
            const float hh = fmaxf(cand, 0.0f);              // relu
            const float hn = z * hold[q] + (1.0f - z) * hh;
            hf_o[(long)m * UU + u] = hn;
            if (c < 7) hb_o[(long)m * UU + u] = __float2bfloat16(hn);
        }

        if (c < 7) grid_sync_(bar, (unsigned)(c + 1));
    }
}

extern "C" void kernel_launch(void* const* d_in, const int* in_sizes, int n_in,
                              void* d_out, int out_size, void* d_ws, size_t ws_size,
                              hipStream_t stream)
{
    const float* x     = (const float*)d_in[0];   // [256,192,512]
    const float* ker   = (const float*)d_in[1];   // [512,1536]
    const float* rker  = (const float*)d_in[2];   // [512,1536]
    const float* ibias = (const float*)d_in[3];   // [1536]
    const float* rbias = (const float*)d_in[4];   // [1536]
    float* out = (float*)d_out;                   // [256,512]

    char* ws = (char*)d_ws;
    float*          MX   = (float*)ws;                            // 12,582,912 B
    __hip_bfloat16* Xb   = (__hip_bfloat16*)(ws + 12582912);      //  2,097,152 B
    __hip_bfloat16* Kt   = (__hip_bfloat16*)(ws + 14680064);      //  1,572,864 B
    __hip_bfloat16* Rt   = (__hip_bfloat16*)(ws + 16252928);      //  1,572,864 B
    float*          hfA  = (float*)(ws + 17825792);               //    524,288 B
    __hip_bfloat16* hbA  = (__hip_bfloat16*)(ws + 18350080);      //    262,144 B
    float*          hfB  = (float*)(ws + 18612224);               //    524,288 B
    __hip_bfloat16* hbB  = (__hip_bfloat16*)(ws + 19136512);      //    262,144 B
    unsigned*       bar  = (unsigned*)(ws + 19398656);            //          8 B

    // Phase 0: weight transposes + x gather/convert + barrier init
    transpose_bf16<<<dim3(48, 16), dim3(32, 8), 0, stream>>>(ker,  Kt, 512, 1536);
    transpose_bf16<<<dim3(48, 16), dim3(32, 8), 0, stream>>>(rker, Rt, 512, 1536);
    convert_x<<<512, 256, 0, stream>>>(x, Xb);
    bar_init<<<1, 64, 0, stream>>>(bar);

    // Phase 1: MX = Xsel @ kernel + input_bias
    gemm_mx<<<dim3(N3 / 64, 2048 / 64), 256, 0, stream>>>(Xb, Kt, ibias, MX);

    // Phase 2: all 8 GRU steps in one persistent kernel (grid barrier between
    // steps; step 0 folds the h0==0 case). Step 0 writes the B buffers.
    gru_chain<<<NWG, 256, 0, stream>>>(Rt, rbias, MX, hfA, hbA, hfB, hbB, out, bar);
}